// Round 5
// baseline (3076.526 us; speedup 1.0000x reference)
//
#include <hip/hip_runtime.h>
#include <hip/hip_bf16.h>

#define NN 50000
#define EE 100000
#define LL 2
#define GRID 1280
#define STRIDE 5120   // GRID * 4 waves/block

typedef __attribute__((ext_vector_type(8))) short short8;
typedef __attribute__((ext_vector_type(4))) float f32x4;

__device__ __forceinline__ short f2bf(float x) {
    __hip_bfloat16 b = __float2bfloat16(x);   // HW RNE
    short s;
    __builtin_memcpy(&s, &b, 2);
    return s;
}

// ---------------- CSR / prep kernels ----------------

__global__ __launch_bounds__(256)
void count_kernel(const int* __restrict__ tgt, int* __restrict__ cnt) {
    int e = blockIdx.x * 256 + threadIdx.x;
    if (e < EE) atomicAdd(&cnt[tgt[e]], 1);
}

__global__ __launch_bounds__(1024)
void scan_kernel(const int* __restrict__ cnt, int* __restrict__ off) {
    __shared__ int tmp[1024];
    __shared__ int carry;
    if (threadIdx.x == 0) carry = 0;
    __syncthreads();
    for (int base = 0; base < NN; base += 1024) {
        int i = base + threadIdx.x;
        int v = (i < NN) ? cnt[i] : 0;
        tmp[threadIdx.x] = v;
        __syncthreads();
        for (int d = 1; d < 1024; d <<= 1) {
            int t = (threadIdx.x >= d) ? tmp[threadIdx.x - d] : 0;
            __syncthreads();
            tmp[threadIdx.x] += t;
            __syncthreads();
        }
        int incl = tmp[threadIdx.x] + carry;
        if (i < NN) off[i + 1] = incl;
        __syncthreads();
        if (threadIdx.x == 1023) carry = incl;
        __syncthreads();
    }
    if (threadIdx.x == 0) off[0] = 0;
}

__global__ __launch_bounds__(256)
void fill_kernel(const int* __restrict__ tgt, const int* __restrict__ off,
                 int* __restrict__ fil, int* __restrict__ eidx) {
    int e = blockIdx.x * 256 + threadIdx.x;
    if (e < EE) {
        int t = tgt[e];
        int s = atomicAdd(&fil[t], 1);
        eidx[off[t] + s] = e;
    }
}

__global__ __launch_bounds__(256)
void recip_kernel(const int* __restrict__ cnt, float* __restrict__ rcnt) {
    int n = blockIdx.x * 256 + threadIdx.x;
    if (n < NN) rcnt[n] = 1.0f / fmaxf((float)cnt[n], 1.0f);
}

__global__ __launch_bounds__(256)
void embed_kernel(const float* __restrict__ x, const float* __restrict__ nw,
                  const float* __restrict__ nb, float* __restrict__ h0) {
    int gid = blockIdx.x * 256 + threadIdx.x;
    if (gid >= NN * 512) return;
    int n = gid >> 9, j = gid & 511;
    h0[gid] = x[n * 8 + (j >> 6)] * nw[j] + nb[j];
}

// Build bf16 B-fragments for all weights.
// Frag f (1024 B): lane l, elem j holds W[nt*16 + (l&15)][ks*32 + (l>>4)*8 + j]
// Order: f 0..7 bproj | 8..31 ipw | 32..39 opw | 40..47 ff1 | 48..55 ff2.
__global__ __launch_bounds__(256)
void prep_frags(const float* __restrict__ bpw, const float* __restrict__ ipw,
                const float* __restrict__ opw, const float* __restrict__ f1w,
                const float* __restrict__ f2w, short* __restrict__ wtb) {
    int gid = blockIdx.x * 256 + threadIdx.x;
    if (gid >= LL * 28672) return;
    int l = gid / 28672, u = gid % 28672;
    int f = u >> 9;
    int el = u & 511;
    int ln = el >> 3, j = el & 7;
    int row16 = ln & 15, kg = ln >> 4;
    const float* W;
    int t;
    if (f < 8)       { W = bpw + l * 4096;  t = f; }
    else if (f < 32) { W = ipw + l * 12288; t = f - 8; }
    else if (f < 40) { W = opw + l * 4096;  t = f - 32; }
    else if (f < 48) { W = f1w + l * 4096;  t = f - 40; }
    else             { W = f2w + l * 4096;  t = f - 48; }
    int nt = t >> 1, ks = t & 1;
    int r = nt * 16 + row16, col = ks * 32 + kg * 8 + j;
    wtb[(size_t)l * 28672 + u] = f2bf(W[r * 64 + col]);
}

// ---------------- fused per-edge layer kernel (MFMA + async prefetch) ----------------

__device__ __forceinline__ void ln64(float x[4][4], const float* gv, const float* bv, int c) {
    float gg[4], bb[4];
#pragma unroll
    for (int nt = 0; nt < 4; nt++) { gg[nt] = gv[nt * 16 + c]; bb[nt] = bv[nt * 16 + c]; }
#pragma unroll
    for (int r = 0; r < 4; r++) {
        float s1 = x[0][r] + x[1][r] + x[2][r] + x[3][r];
        float s2 = x[0][r] * x[0][r];
#pragma unroll
        for (int nt = 1; nt < 4; nt++) s2 = fmaf(x[nt][r], x[nt][r], s2);
#pragma unroll
        for (int m = 1; m < 16; m <<= 1) { s1 += __shfl_xor(s1, m); s2 += __shfl_xor(s2, m); }
        float mean = s1 * 0.015625f;
        float var = fmaf(s2, 0.015625f, -mean * mean);
        float rs = rsqrtf(var + 1e-5f);
#pragma unroll
        for (int nt = 0; nt < 4; nt++) x[nt][r] = fmaf((x[nt][r] - mean) * rs, gg[nt], bb[nt]);
    }
}

// async-prefetch the fp32 X-tile [16 rows][64 f32] (rows 0-7 = h[tn], 8-15 = h[sn])
// into bufX with 16B-granule swizzle: stored(row,q) = logical(row, q ^ (row&15)).
__device__ __forceinline__ void pf_tile(char* bufX, const float* h, int tn, int sn, int lane) {
    const char* bt = (const char*)(h + (size_t)tn * 512);
    const char* bs = (const char*)(h + (size_t)sn * 512);
    int rhi = lane >> 4, q = lane & 15;
#define PF1(m, base) { \
    int row = (m) * 4 + rhi; \
    int so = ((row & 7) << 8) + (((q ^ row) & 15) << 4); \
    __builtin_amdgcn_global_load_lds((const __attribute__((address_space(1))) void*)((base) + so), \
        (__attribute__((address_space(3))) void*)(bufX + (m) * 1024), 16, 0, 0); }
    PF1(0, bt) PF1(1, bt) PF1(2, bs) PF1(3, bs)
#undef PF1
}

// read MFMA A-frag (row=c, elems ks*32 + g*8 .. +8) from swizzled fp32 tile, cvt to bf16
__device__ __forceinline__ short8 ldaf32(const char* B, int ks, int g, int c) {
    int off = (ks * 128 + g * 32) ^ (c << 4);
    float4 lo = *(const float4*)(B + c * 256 + off);
    float4 hi = *(const float4*)(B + c * 256 + (off ^ 16));
    short8 r;
    r[0] = f2bf(lo.x); r[1] = f2bf(lo.y); r[2] = f2bf(lo.z); r[3] = f2bf(lo.w);
    r[4] = f2bf(hi.x); r[5] = f2bf(hi.y); r[6] = f2bf(hi.z); r[7] = f2bf(hi.w);
    return r;
}

__global__ __launch_bounds__(256, 5)
void layer_kernel(const float* __restrict__ h_in, short* __restrict__ msgp,
                  const int* __restrict__ src, const int* __restrict__ tgt,
                  const short* __restrict__ wfr,
                  const float* __restrict__ bpb, const float* __restrict__ ipb,
                  const float* __restrict__ opb,
                  const float* __restrict__ g1v, const float* __restrict__ b1v,
                  const float* __restrict__ g2v, const float* __restrict__ b2v,
                  const float* __restrict__ f1b, const float* __restrict__ f2b)
{
    // LDS: 4 waves x (bufX 4KB fp32 X-tile -> K/Q bf16 tiles, bufB 2KB O/x1/f). No shared region.
    __shared__ __align__(16) char smem[24576];
    const int tid = threadIdx.x, wv = tid >> 6, lane = tid & 63;
    const int g = lane >> 4, c = lane & 15;
    const int swz = (c & 7) << 4;

    char* bufX = smem + wv * 6144;
    char* bufB = bufX + 4096;
    const short8* gw = (const short8*)wfr;   // all weight frags from global (L2-hot)
    const f32x4 zf = {};
    const short8 z8 = {};

#define LDA(B, ks)  (*(const short8*)&(B)[c * 128 + (((ks) * 64 + g * 16) ^ swz)])
#define LDH(B, h)   (*(const short8*)&(B)[c * 128 + (((h) * 32 + (g & 1) * 16) ^ swz)])
#define GFRAG(f)    (gw[(f) * 64 + lane])
#define MFMA(a, b, cc) __builtin_amdgcn_mfma_f32_16x16x32_bf16((a), (b), (cc), 0, 0, 0)

    int e = blockIdx.x * 4 + wv;          // < 5120 <= EE always
    int sn = src[e], tn = tgt[e];
    pf_tile(bufX, h_in, tn, sn, lane);

    for (; e < EE; e += STRIDE) {
        int en = e + STRIDE; if (en >= EE) en = e;
        int sn1 = src[en], tn1 = tgt[en];

        // ensure the prefetched X-tile has landed
        asm volatile("s_waitcnt vmcnt(0)" ::: "memory");

        // residual x_i from LDS fp32 tile rows 0..7 (lanes<32), before S2 overwrites
        float xc[4][4];
        if (lane < 32) {
#pragma unroll
            for (int nt = 0; nt < 4; nt++)
#pragma unroll
                for (int r = 0; r < 4; r++) {
                    int row = g * 4 + r;   // 0..7
                    xc[nt][r] = *(const float*)&bufX[row * 256 + (((nt * 16 + c) * 4) ^ ((row & 15) << 4))];
                }
        }

        // ---- S1: bproj -> rows 8..15 (fp32, written back into bufX) ----
        short8 a0 = ldaf32(bufX, 0, g, c), a1 = ldaf32(bufX, 1, g, c);
#pragma unroll
        for (int nt = 0; nt < 4; nt++) {
            f32x4 acc = MFMA(a1, GFRAG(nt * 2 + 1),
                        MFMA(a0, GFRAG(nt * 2 + 0), zf));
            if (lane >= 32) {
                float bb = bpb[nt * 16 + c];
#pragma unroll
                for (int r = 0; r < 4; r++) {
                    float y = acc[r] + bb;
                    xc[nt][r] = y;
                    int row = g * 4 + r;   // 8..15
                    *(float*)&bufX[row * 256 + (((nt * 16 + c) * 4) ^ ((row & 15) << 4))] = y;
                }
            }
        }

        // ---- S2: in_proj -> Q,K,V ----
        a0 = ldaf32(bufX, 0, g, c); a1 = ldaf32(bufX, 1, g, c);
        f32x4 qv[4], kv[4], vv[4];
#pragma unroll
        for (int nt = 0; nt < 4; nt++) {
            qv[nt] = MFMA(a1, GFRAG(8 + nt * 2 + 1),        MFMA(a0, GFRAG(8 + nt * 2 + 0),        zf));
            kv[nt] = MFMA(a1, GFRAG(8 + (nt + 4) * 2 + 1),  MFMA(a0, GFRAG(8 + (nt + 4) * 2 + 0),  zf));
            vv[nt] = MFMA(a1, GFRAG(8 + (nt + 8) * 2 + 1),  MFMA(a0, GFRAG(8 + (nt + 8) * 2 + 0),  zf));
        }
        // K tile -> bufX[0:2048], Q tile -> bufX[2048:4096] (bf16, swizzled); V + bias in regs
#pragma unroll
        for (int nt = 0; nt < 4; nt++) {
            float bq = ipb[nt * 16 + c], bk = ipb[(nt + 4) * 16 + c], bv = ipb[(nt + 8) * 16 + c];
#pragma unroll
            for (int r = 0; r < 4; r++) {
                int row = g * 4 + r;
                int sw = (row & 7) << 4;
                int cb = (nt * 16 + c) * 2;
                *(short*)&bufX[row * 128 + (cb ^ sw)] = f2bf(kv[nt][r] + bk);
                *(short*)&bufX[2048 + row * 128 + (cb ^ sw)] = f2bf(qv[nt][r] + bq);
                vv[nt][r] += bv;
            }
        }

        // ---- S3: attention, S^T = K @ Q^T ----
        float ov[4][4];
#pragma unroll
        for (int h = 0; h < 4; h++) {
            short8 kf = LDH(bufX, h);
            short8 qf = LDH(bufX + 2048, h);
            if (lane >= 32) kf = z8;
            f32x4 st = MFMA(kf, qf, zf);
            float p[4];
#pragma unroll
            for (int r = 0; r < 4; r++) p[r] = st[r] * 0.25f;
            float m4 = fmaxf(fmaxf(p[0], p[1]), fmaxf(p[2], p[3]));
            m4 = fmaxf(m4, __shfl_xor(m4, 16));
            m4 = fmaxf(m4, __shfl_xor(m4, 32));
            float s4 = 0.f;
#pragma unroll
            for (int r = 0; r < 4; r++) { p[r] = __expf(p[r] - m4); s4 += p[r]; }
            s4 += __shfl_xor(s4, 16);
            s4 += __shfl_xor(s4, 32);
            float inv = 1.0f / s4;
#pragma unroll
            for (int r = 0; r < 4; r++) p[r] *= inv;
            short8 pa, vb;
#pragma unroll
            for (int j = 0; j < 8; j++) {
                int srcl = g * 32 + ((j >> 2) << 4) + c;
                pa[j] = f2bf(__shfl(p[j & 3], srcl));
                vb[j] = f2bf(__shfl(vv[h][j & 3], srcl));
            }
            if (lane >= 32) pa = z8;
            f32x4 o = MFMA(pa, vb, zf);
#pragma unroll
            for (int r = 0; r < 4; r++) ov[h][r] = o[r];
        }
        // O tile -> bufB
#pragma unroll
        for (int h = 0; h < 4; h++)
#pragma unroll
            for (int r = 0; r < 4; r++) {
                int row = g * 4 + r;
                *(short*)&bufB[row * 128 + (((h * 16 + c) * 2) ^ ((row & 7) << 4))] = f2bf(ov[h][r]);
            }

        // ---- issue async prefetch for next edge (bufX fully dead now) ----
        pf_tile(bufX, h_in, tn1, sn1, lane);

        // ---- S4: out_proj + residual + LN1 ----
        a0 = LDA(bufB, 0); a1 = LDA(bufB, 1);
        float x1[4][4];
#pragma unroll
        for (int nt = 0; nt < 4; nt++) {
            f32x4 acc = MFMA(a1, GFRAG(32 + nt * 2 + 1),
                        MFMA(a0, GFRAG(32 + nt * 2 + 0), zf));
            float bo = opb[nt * 16 + c];
#pragma unroll
            for (int r = 0; r < 4; r++) x1[nt][r] = acc[r] + bo + xc[nt][r];
        }
        ln64(x1, g1v, b1v, c);

        // ---- S5: FF ----
#pragma unroll
        for (int nt = 0; nt < 4; nt++)
#pragma unroll
            for (int r = 0; r < 4; r++) {
                int row = g * 4 + r;
                *(short*)&bufB[row * 128 + (((nt * 16 + c) * 2) ^ ((row & 7) << 4))] = f2bf(x1[nt][r]);
            }
        a0 = LDA(bufB, 0); a1 = LDA(bufB, 1);
#pragma unroll
        for (int nt = 0; nt < 4; nt++) {
            f32x4 acc = MFMA(a1, GFRAG(40 + nt * 2 + 1),
                        MFMA(a0, GFRAG(40 + nt * 2 + 0), zf));
            float bf = f1b[nt * 16 + c];
#pragma unroll
            for (int r = 0; r < 4; r++) {
                float y = fmaxf(acc[r] + bf, 0.0f);
                int row = g * 4 + r;
                *(short*)&bufB[row * 128 + (((nt * 16 + c) * 2) ^ ((row & 7) << 4))] = f2bf(y);
            }
        }
        a0 = LDA(bufB, 0); a1 = LDA(bufB, 1);
        float x2[4][4];
#pragma unroll
        for (int nt = 0; nt < 4; nt++) {
            f32x4 acc = MFMA(a1, GFRAG(48 + nt * 2 + 1),
                        MFMA(a0, GFRAG(48 + nt * 2 + 0), zf));
            float bf = f2b[nt * 16 + c];
#pragma unroll
            for (int r = 0; r < 4; r++) x2[nt][r] = acc[r] + bf + x1[nt][r];
        }
        ln64(x2, g2v, b2v, c);

        // ---- S6: pack msg row (bf16, lane-contiguous C/D-native layout) ----
        // element m = lane*16 + nt*4 + r  <->  token (lane>>4)*4+r, feat nt*16+(lane&15)
        if (lane < 32) {
            unsigned w[8];
#pragma unroll
            for (int nt = 0; nt < 4; nt++) {
                unsigned a = (unsigned)(unsigned short)f2bf(x2[nt][0]);
                unsigned b = (unsigned)(unsigned short)f2bf(x2[nt][1]);
                unsigned cc2 = (unsigned)(unsigned short)f2bf(x2[nt][2]);
                unsigned d = (unsigned)(unsigned short)f2bf(x2[nt][3]);
                w[nt * 2]     = a | (b << 16);
                w[nt * 2 + 1] = cc2 | (d << 16);
            }
            char* me = (char*)(msgp + (size_t)e * 512) + lane * 32;
            ((int4*)me)[0] = make_int4(w[0], w[1], w[2], w[3]);
            ((int4*)me)[1] = make_int4(w[4], w[5], w[6], w[7]);
        }

        sn = sn1; tn = tn1;
    }
#undef LDA
#undef LDH
#undef GFRAG
#undef MFMA
}

// ---------------- aggregation: wave per node, coalesced msg reads ----------------

__global__ __launch_bounds__(256)
void aggr_kernel(const short* __restrict__ msgp, const int* __restrict__ off,
                 const int* __restrict__ eidx, const float* __restrict__ rcnt,
                 float* __restrict__ h) {
    int n = blockIdx.x * 4 + (threadIdx.x >> 6);
    if (n >= NN) return;
    int lane = threadIdx.x & 63;
    int b = off[n], t = off[n + 1];
    float acc[8] = {0, 0, 0, 0, 0, 0, 0, 0};
    for (int s = b; s < t; s++) {
        int e = eidx[s];
        short8 mv = *(const short8*)&msgp[(size_t)e * 512 + lane * 8];
#pragma unroll
        for (int j = 0; j < 8; j++)
            acc[j] += __uint_as_float(((unsigned)(unsigned short)mv[j]) << 16);
    }
    float rc = rcnt[n];
    float* hn = h + (size_t)n * 512;
#pragma unroll
    for (int j = 0; j < 8; j++) {
        int m = lane * 8 + j;
        int ls = m >> 4, u = m & 15;
        int hidx = ((ls >> 4) * 4 + (u & 3)) * 64 + (u >> 2) * 16 + (ls & 15);
        hn[hidx] = acc[j] * rc;
    }
}

// ---------------- final projection + softmax ----------------

__global__ __launch_bounds__(256)
void out_kernel(const float* __restrict__ h, const float* __restrict__ ow,
                const float* __restrict__ ob, float* __restrict__ out)
{
    __shared__ __align__(16) float hl[16 * 516];
    __shared__ __align__(16) float wl[16 * 68];
    __shared__ float bl[16];
    const int tid = threadIdx.x;
    const int n0 = blockIdx.x * 16;
#pragma unroll
    for (int i = 0; i < 4; i++) {
        int idx = i * 256 + tid;
        wl[(idx >> 6) * 68 + (idx & 63)] = ow[idx];
    }
    if (tid < 16) bl[tid] = ob[tid];
#pragma unroll
    for (int i = 0; i < 32; i++) {
        int idx = i * 256 + tid; int nl = idx >> 9, j = idx & 511;
        hl[nl * 516 + j] = h[(size_t)(n0 + nl) * 512 + j];
    }
    __syncthreads();
    const int nl = tid >> 4, o = tid & 15;
    float acc = 0;
#pragma unroll 4
    for (int d4 = 0; d4 < 16; d4++) {
        float4 wv = *(const float4*)&wl[o * 68 + d4 * 4];
#pragma unroll
        for (int cc = 0; cc < 8; cc++) {
            float4 hv = *(const float4*)&hl[nl * 516 + cc * 64 + d4 * 4];
            acc += hv.x * wv.x + hv.y * wv.y + hv.z * wv.z + hv.w * wv.w;
        }
    }
    float z = acc + 8.0f * bl[o];
    float mxv = z;
#pragma unroll
    for (int m = 1; m < 16; m <<= 1) mxv = fmaxf(mxv, __shfl_xor(mxv, m));
    float ez = __expf(z - mxv);
    float sm = ez;
#pragma unroll
    for (int m = 1; m < 16; m <<= 1) sm += __shfl_xor(sm, m);
    out[(size_t)(n0 + nl) * 16 + o] = ez / sm;
}

// ---------------- launch ----------------

extern "C" void kernel_launch(void* const* d_in, const int* in_sizes, int n_in,
                              void* d_out, int out_size, void* d_ws, size_t ws_size,
                              hipStream_t stream)
{
    const float* x   = (const float*)d_in[0];
    const int*   ei  = (const int*)d_in[1];
    const float* nw  = (const float*)d_in[2];
    const float* nb  = (const float*)d_in[3];
    const float* bpw = (const float*)d_in[4];
    const float* bpb = (const float*)d_in[5];
    const float* ipw = (const float*)d_in[6];
    const float* ipb = (const float*)d_in[7];
    const float* opw = (const float*)d_in[8];
    const float* opb = (const float*)d_in[9];
    const float* g1  = (const float*)d_in[10];
    const float* b1  = (const float*)d_in[11];
    const float* g2  = (const float*)d_in[12];
    const float* b2  = (const float*)d_in[13];
    const float* f1w = (const float*)d_in[14];
    const float* f1b = (const float*)d_in[15];
    const float* f2w = (const float*)d_in[16];
    const float* f2b = (const float*)d_in[17];
    const float* ow  = (const float*)d_in[18];
    const float* ob  = (const float*)d_in[19];

    float* h0   = (float*)d_ws;                     // 25,600,000 f32
    short* msg  = (short*)(h0 + (size_t)NN * 512);  // 51,200,000 bf16
    int*   cnt  = (int*)(msg + (size_t)EE * 512);   // 50,000
    int*   off  = cnt + 50000;                      // 50,004 (padded)
    int*   fil  = off + 50004;                      // 50,000
    int*   eidx = fil + 50000;                      // 100,000
    float* rcnt = (float*)(eidx + 100000);          // 50,000
    short* wtb  = (short*)(rcnt + 50000);           // 2*28,672 (16B-aligned)

    // CSR build (edge_index constant; rebuilt every call for graph-capture safety)
    hipMemsetAsync(cnt, 0, 50000 * sizeof(int), stream);
    hipMemsetAsync(fil, 0, 50000 * sizeof(int), stream);
    count_kernel<<<(EE + 255) / 256, 256, 0, stream>>>(ei + EE, cnt);
    scan_kernel<<<1, 1024, 0, stream>>>(cnt, off);
    fill_kernel<<<(EE + 255) / 256, 256, 0, stream>>>(ei + EE, off, fil, eidx);
    recip_kernel<<<(NN + 255) / 256, 256, 0, stream>>>(cnt, rcnt);
    prep_frags<<<(LL * 28672 + 255) / 256, 256, 0, stream>>>(bpw, ipw, opw, f1w, f2w, wtb);
    embed_kernel<<<(NN * 512) / 256, 256, 0, stream>>>(x, nw, nb, h0);

    layer_kernel<<<GRID, 256, 0, stream>>>(h0, msg, ei, ei + EE, wtb,
                                           bpb, ipb, opb, g1, b1, g2, b2, f1b, f2b);
    aggr_kernel<<<(NN + 3) / 4, 256, 0, stream>>>(msg, off, eidx, rcnt, h0);
    layer_kernel<<<GRID, 256, 0, stream>>>(h0, msg, ei, ei + EE, wtb + 28672,
                                           bpb + 64, ipb + 192, opb + 64,
                                           g1 + 64, b1 + 64, g2 + 64, b2 + 64, f1b + 64, f2b + 64);
    aggr_kernel<<<(NN + 3) / 4, 256, 0, stream>>>(msg, off, eidx, rcnt, h0);
    out_kernel<<<NN / 16, 256, 0, stream>>>(h0, ow, ob, (float*)d_out);
}

// Round 6
// 1126.289 us; speedup vs baseline: 2.7316x; 2.7316x over previous
//
#include <hip/hip_runtime.h>
#include <hip/hip_bf16.h>

#define NN 50000
#define EE 100000
#define LL 2
#define GRID 256
#define STRIDE 4096   // GRID * 16 waves/block

typedef __attribute__((ext_vector_type(8))) short short8;
typedef __attribute__((ext_vector_type(4))) float f32x4;

__device__ __forceinline__ short f2bf(float x) {
    __hip_bfloat16 b = __float2bfloat16(x);   // HW RNE
    short s;
    __builtin_memcpy(&s, &b, 2);
    return s;
}

// ---------------- CSR / prep kernels ----------------

__global__ __launch_bounds__(256)
void count_kernel(const int* __restrict__ tgt, int* __restrict__ cnt) {
    int e = blockIdx.x * 256 + threadIdx.x;
    if (e < EE) atomicAdd(&cnt[tgt[e]], 1);
}

__global__ __launch_bounds__(1024)
void scan_kernel(const int* __restrict__ cnt, int* __restrict__ off) {
    __shared__ int tmp[1024];
    __shared__ int carry;
    if (threadIdx.x == 0) carry = 0;
    __syncthreads();
    for (int base = 0; base < NN; base += 1024) {
        int i = base + threadIdx.x;
        int v = (i < NN) ? cnt[i] : 0;
        tmp[threadIdx.x] = v;
        __syncthreads();
        for (int d = 1; d < 1024; d <<= 1) {
            int t = (threadIdx.x >= d) ? tmp[threadIdx.x - d] : 0;
            __syncthreads();
            tmp[threadIdx.x] += t;
            __syncthreads();
        }
        int incl = tmp[threadIdx.x] + carry;
        if (i < NN) off[i + 1] = incl;
        __syncthreads();
        if (threadIdx.x == 1023) carry = incl;
        __syncthreads();
    }
    if (threadIdx.x == 0) off[0] = 0;
}

__global__ __launch_bounds__(256)
void fill_kernel(const int* __restrict__ tgt, const int* __restrict__ off,
                 int* __restrict__ fil, int* __restrict__ eidx) {
    int e = blockIdx.x * 256 + threadIdx.x;
    if (e < EE) {
        int t = tgt[e];
        int s = atomicAdd(&fil[t], 1);
        eidx[off[t] + s] = e;
    }
}

__global__ __launch_bounds__(256)
void recip_kernel(const int* __restrict__ cnt, float* __restrict__ rcnt) {
    int n = blockIdx.x * 256 + threadIdx.x;
    if (n < NN) rcnt[n] = 1.0f / fmaxf((float)cnt[n], 1.0f);
}

__global__ __launch_bounds__(256)
void embed_kernel(const float* __restrict__ x, const float* __restrict__ nw,
                  const float* __restrict__ nb, float* __restrict__ h0) {
    int gid = blockIdx.x * 256 + threadIdx.x;
    if (gid >= NN * 512) return;
    int n = gid >> 9, j = gid & 511;
    h0[gid] = x[n * 8 + (j >> 6)] * nw[j] + nb[j];
}

// Build bf16 B-fragments for all weights.
// Frag f (1024 B): lane l, elem j holds W[nt*16 + (l&15)][ks*32 + (l>>4)*8 + j]
// Order: f 0..7 bproj | 8..31 ipw | 32..39 opw | 40..47 ff1 | 48..55 ff2.
__global__ __launch_bounds__(256)
void prep_frags(const float* __restrict__ bpw, const float* __restrict__ ipw,
                const float* __restrict__ opw, const float* __restrict__ f1w,
                const float* __restrict__ f2w, short* __restrict__ wtb) {
    int gid = blockIdx.x * 256 + threadIdx.x;
    if (gid >= LL * 28672) return;
    int l = gid / 28672, u = gid % 28672;
    int f = u >> 9;
    int el = u & 511;
    int ln = el >> 3, j = el & 7;
    int row16 = ln & 15, kg = ln >> 4;
    const float* W;
    int t;
    if (f < 8)       { W = bpw + l * 4096;  t = f; }
    else if (f < 32) { W = ipw + l * 12288; t = f - 8; }
    else if (f < 40) { W = opw + l * 4096;  t = f - 32; }
    else if (f < 48) { W = f1w + l * 4096;  t = f - 40; }
    else             { W = f2w + l * 4096;  t = f - 48; }
    int nt = t >> 1, ks = t & 1;
    int r = nt * 16 + row16, col = ks * 32 + kg * 8 + j;
    wtb[(size_t)l * 28672 + u] = f2bf(W[r * 64 + col]);
}

// ---------------- fused per-edge layer kernel (MFMA + async prefetch) ----------------

__device__ __forceinline__ void ln64(float x[4][4], const float* gv, const float* bv, int c) {
    float gg[4], bb[4];
#pragma unroll
    for (int nt = 0; nt < 4; nt++) { gg[nt] = gv[nt * 16 + c]; bb[nt] = bv[nt * 16 + c]; }
#pragma unroll
    for (int r = 0; r < 4; r++) {
        float s1 = x[0][r] + x[1][r] + x[2][r] + x[3][r];
        float s2 = x[0][r] * x[0][r];
#pragma unroll
        for (int nt = 1; nt < 4; nt++) s2 = fmaf(x[nt][r], x[nt][r], s2);
#pragma unroll
        for (int m = 1; m < 16; m <<= 1) { s1 += __shfl_xor(s1, m); s2 += __shfl_xor(s2, m); }
        float mean = s1 * 0.015625f;
        float var = fmaf(s2, 0.015625f, -mean * mean);
        float rs = rsqrtf(var + 1e-5f);
#pragma unroll
        for (int nt = 0; nt < 4; nt++) x[nt][r] = fmaf((x[nt][r] - mean) * rs, gg[nt], bb[nt]);
    }
}

// async-prefetch the fp32 X-tile [16 rows][64 f32] (rows 0-7 = h[tn], 8-15 = h[sn])
// into bufX with 16B-granule swizzle: stored(row,q) = logical(row, q ^ (row&15)).
__device__ __forceinline__ void pf_tile(char* bufX, const float* h, int tn, int sn, int lane) {
    const char* bt = (const char*)(h + (size_t)tn * 512);
    const char* bs = (const char*)(h + (size_t)sn * 512);
    int rhi = lane >> 4, q = lane & 15;
#define PF1(m, base) { \
    int row = (m) * 4 + rhi; \
    int so = ((row & 7) << 8) + (((q ^ row) & 15) << 4); \
    __builtin_amdgcn_global_load_lds((const __attribute__((address_space(1))) void*)((base) + so), \
        (__attribute__((address_space(3))) void*)(bufX + (m) * 1024), 16, 0, 0); }
    PF1(0, bt) PF1(1, bt) PF1(2, bs) PF1(3, bs)
#undef PF1
}

// read MFMA A-frag (row=c, elems ks*32 + g*8 .. +8) from swizzled fp32 tile, cvt to bf16
__device__ __forceinline__ short8 ldaf32(const char* B, int ks, int g, int c) {
    int off = (ks * 128 + g * 32) ^ (c << 4);
    float4 lo = *(const float4*)(B + c * 256 + off);
    float4 hi = *(const float4*)(B + c * 256 + (off ^ 16));
    short8 r;
    r[0] = f2bf(lo.x); r[1] = f2bf(lo.y); r[2] = f2bf(lo.z); r[3] = f2bf(lo.w);
    r[4] = f2bf(hi.x); r[5] = f2bf(hi.y); r[6] = f2bf(hi.z); r[7] = f2bf(hi.w);
    return r;
}

// LDS map: [0,57344) 56 weight frags | [57344,60160) biases (704 f32) | 16 x 6144 per-wave bufs
#define LDS_TOTAL (60160 + 16 * 6144)

__global__ __launch_bounds__(1024)
void layer_kernel(const float* __restrict__ h_in, short* __restrict__ msgp,
                  const int* __restrict__ src, const int* __restrict__ tgt,
                  const short* __restrict__ wfr,
                  const float* __restrict__ bpb, const float* __restrict__ ipb,
                  const float* __restrict__ opb,
                  const float* __restrict__ g1v, const float* __restrict__ b1v,
                  const float* __restrict__ g2v, const float* __restrict__ b2v,
                  const float* __restrict__ f1b, const float* __restrict__ f2b)
{
    __shared__ __align__(16) char smem[LDS_TOTAL];
    const int tid = threadIdx.x, wv = tid >> 6, lane = tid & 63;
    const int g = lane >> 4, c = lane & 15;
    const int swz = (c & 7) << 4;

    {   // stage all 56 weight frags (57344 B) + biases into LDS once
        const int4* sw4 = (const int4*)wfr;
        int4* dw4 = (int4*)smem;
        for (int i = tid; i < 3584; i += 1024) dw4[i] = sw4[i];
        float* bl = (float*)(smem + 57344);
        if (tid < 704) {
            float v;
            if (tid < 64)       v = bpb[tid];
            else if (tid < 256) v = ipb[tid - 64];
            else if (tid < 320) v = opb[tid - 256];
            else if (tid < 384) v = g1v[tid - 320];
            else if (tid < 448) v = b1v[tid - 384];
            else if (tid < 512) v = g2v[tid - 448];
            else if (tid < 576) v = b2v[tid - 512];
            else if (tid < 640) v = f1b[tid - 576];
            else                v = f2b[tid - 640];
            bl[tid] = v;
        }
    }

    char* bufX = smem + 60160 + wv * 6144;
    char* bufB = bufX + 4096;
    const float* bias = (const float*)(smem + 57344);
    const float* BPB = bias;
    const float* IPB = bias + 64;
    const float* OPB = bias + 256;
    const float* G1  = bias + 320;
    const float* B1  = bias + 384;
    const float* G2  = bias + 448;
    const float* B2  = bias + 512;
    const float* F1B = bias + 576;
    const float* F2B = bias + 640;
    const f32x4 zf = {};
    const short8 z8 = {};

#define LDA(B, ks)  (*(const short8*)&(B)[c * 128 + (((ks) * 64 + g * 16) ^ swz)])
#define LDH(B, h)   (*(const short8*)&(B)[c * 128 + (((h) * 32 + (g & 1) * 16) ^ swz)])
#define LFRAG(f)    (*(const short8*)&smem[(f) * 1024 + lane * 16])
#define MFMA(a, b, cc) __builtin_amdgcn_mfma_f32_16x16x32_bf16((a), (b), (cc), 0, 0, 0)

    int e = blockIdx.x * 16 + wv;         // < 4096 <= EE always
    int sn = src[e], tn = tgt[e];
    pf_tile(bufX, h_in, tn, sn, lane);
    __syncthreads();   // weights staged (also drains prefetch; first-iter wait is redundant)

    for (; e < EE; e += STRIDE) {
        int en = e + STRIDE; if (en >= EE) en = e;
        int sn1 = src[en], tn1 = tgt[en];

        // ensure the prefetched X-tile has landed
        asm volatile("s_waitcnt vmcnt(0)" ::: "memory");

        // residual x_i from LDS fp32 tile rows 0..7 (lanes<32), before S2 overwrites
        float xc[4][4];
        if (lane < 32) {
#pragma unroll
            for (int nt = 0; nt < 4; nt++)
#pragma unroll
                for (int r = 0; r < 4; r++) {
                    int row = g * 4 + r;   // 0..7
                    xc[nt][r] = *(const float*)&bufX[row * 256 + (((nt * 16 + c) * 4) ^ ((row & 15) << 4))];
                }
        }

        // ---- S1: bproj -> rows 8..15 (fp32, written back into bufX) ----
        short8 a0 = ldaf32(bufX, 0, g, c), a1 = ldaf32(bufX, 1, g, c);
#pragma unroll
        for (int nt = 0; nt < 4; nt++) {
            f32x4 acc = MFMA(a1, LFRAG(nt * 2 + 1),
                        MFMA(a0, LFRAG(nt * 2 + 0), zf));
            if (lane >= 32) {
                float bb = BPB[nt * 16 + c];
#pragma unroll
                for (int r = 0; r < 4; r++) {
                    float y = acc[r] + bb;
                    xc[nt][r] = y;
                    int row = g * 4 + r;   // 8..15
                    *(float*)&bufX[row * 256 + (((nt * 16 + c) * 4) ^ ((row & 15) << 4))] = y;
                }
            }
        }

        // ---- S2: in_proj -> Q,K,V ----
        a0 = ldaf32(bufX, 0, g, c); a1 = ldaf32(bufX, 1, g, c);
        f32x4 qv[4], kv[4], vv[4];
#pragma unroll
        for (int nt = 0; nt < 4; nt++) {
            qv[nt] = MFMA(a1, LFRAG(8 + nt * 2 + 1),        MFMA(a0, LFRAG(8 + nt * 2 + 0),        zf));
            kv[nt] = MFMA(a1, LFRAG(8 + (nt + 4) * 2 + 1),  MFMA(a0, LFRAG(8 + (nt + 4) * 2 + 0),  zf));
            vv[nt] = MFMA(a1, LFRAG(8 + (nt + 8) * 2 + 1),  MFMA(a0, LFRAG(8 + (nt + 8) * 2 + 0),  zf));
        }
        // K tile -> bufX[0:2048], Q tile -> bufX[2048:4096] (bf16, swizzled); V + bias in regs
#pragma unroll
        for (int nt = 0; nt < 4; nt++) {
            float bq = IPB[nt * 16 + c], bk = IPB[(nt + 4) * 16 + c], bv = IPB[(nt + 8) * 16 + c];
#pragma unroll
            for (int r = 0; r < 4; r++) {
                int row = g * 4 + r;
                int sw = (row & 7) << 4;
                int cb = (nt * 16 + c) * 2;
                *(short*)&bufX[row * 128 + (cb ^ sw)] = f2bf(kv[nt][r] + bk);
                *(short*)&bufX[2048 + row * 128 + (cb ^ sw)] = f2bf(qv[nt][r] + bq);
                vv[nt][r] += bv;
            }
        }

        // ---- S3: attention, S^T = K @ Q^T ----
        float ov[4][4];
#pragma unroll
        for (int h = 0; h < 4; h++) {
            short8 kf = LDH(bufX, h);
            short8 qf = LDH(bufX + 2048, h);
            if (lane >= 32) kf = z8;
            f32x4 st = MFMA(kf, qf, zf);
            float p[4];
#pragma unroll
            for (int r = 0; r < 4; r++) p[r] = st[r] * 0.25f;
            float m4 = fmaxf(fmaxf(p[0], p[1]), fmaxf(p[2], p[3]));
            m4 = fmaxf(m4, __shfl_xor(m4, 16));
            m4 = fmaxf(m4, __shfl_xor(m4, 32));
            float s4 = 0.f;
#pragma unroll
            for (int r = 0; r < 4; r++) { p[r] = __expf(p[r] - m4); s4 += p[r]; }
            s4 += __shfl_xor(s4, 16);
            s4 += __shfl_xor(s4, 32);
            float inv = 1.0f / s4;
#pragma unroll
            for (int r = 0; r < 4; r++) p[r] *= inv;
            short8 pa, vb;
#pragma unroll
            for (int j = 0; j < 8; j++) {
                int srcl = g * 32 + ((j >> 2) << 4) + c;
                pa[j] = f2bf(__shfl(p[j & 3], srcl));
                vb[j] = f2bf(__shfl(vv[h][j & 3], srcl));
            }
            if (lane >= 32) pa = z8;
            f32x4 o = MFMA(pa, vb, zf);
#pragma unroll
            for (int r = 0; r < 4; r++) ov[h][r] = o[r];
        }
        // O tile -> bufB
#pragma unroll
        for (int h = 0; h < 4; h++)
#pragma unroll
            for (int r = 0; r < 4; r++) {
                int row = g * 4 + r;
                *(short*)&bufB[row * 128 + (((h * 16 + c) * 2) ^ ((row & 7) << 4))] = f2bf(ov[h][r]);
            }

        // ---- issue async prefetch for next edge (bufX fully dead now) ----
        pf_tile(bufX, h_in, tn1, sn1, lane);

        // ---- S4: out_proj + residual + LN1 ----
        a0 = LDA(bufB, 0); a1 = LDA(bufB, 1);
        float x1[4][4];
#pragma unroll
        for (int nt = 0; nt < 4; nt++) {
            f32x4 acc = MFMA(a1, LFRAG(32 + nt * 2 + 1),
                        MFMA(a0, LFRAG(32 + nt * 2 + 0), zf));
            float bo = OPB[nt * 16 + c];
#pragma unroll
            for (int r = 0; r < 4; r++) x1[nt][r] = acc[r] + bo + xc[nt][r];
        }
        ln64(x1, G1, B1, c);

        // ---- S5: FF ----
#pragma unroll
        for (int nt = 0; nt < 4; nt++)
#pragma unroll
            for (int r = 0; r < 4; r++) {
                int row = g * 4 + r;
                *(short*)&bufB[row * 128 + (((nt * 16 + c) * 2) ^ ((row & 7) << 4))] = f2bf(x1[nt][r]);
            }
        a0 = LDA(bufB, 0); a1 = LDA(bufB, 1);
#pragma unroll
        for (int nt = 0; nt < 4; nt++) {
            f32x4 acc = MFMA(a1, LFRAG(40 + nt * 2 + 1),
                        MFMA(a0, LFRAG(40 + nt * 2 + 0), zf));
            float bf = F1B[nt * 16 + c];
#pragma unroll
            for (int r = 0; r < 4; r++) {
                float y = fmaxf(acc[r] + bf, 0.0f);
                int row = g * 4 + r;
                *(short*)&bufB[row * 128 + (((nt * 16 + c) * 2) ^ ((row & 7) << 4))] = f2bf(y);
            }
        }
        a0 = LDA(bufB, 0); a1 = LDA(bufB, 1);
        float x2[4][4];
#pragma unroll
        for (int nt = 0; nt < 4; nt++) {
            f32x4 acc = MFMA(a1, LFRAG(48 + nt * 2 + 1),
                        MFMA(a0, LFRAG(48 + nt * 2 + 0), zf));
            float bf = F2B[nt * 16 + c];
#pragma unroll
            for (int r = 0; r < 4; r++) x2[nt][r] = acc[r] + bf + x1[nt][r];
        }
        ln64(x2, G2, B2, c);

        // ---- S6: pack msg row (bf16, lane-contiguous C/D-native layout) ----
        // element m = lane*16 + nt*4 + r  <->  token (lane>>4)*4+r, feat nt*16+(lane&15)
        if (lane < 32) {
            unsigned w[8];
#pragma unroll
            for (int nt = 0; nt < 4; nt++) {
                unsigned a = (unsigned)(unsigned short)f2bf(x2[nt][0]);
                unsigned b = (unsigned)(unsigned short)f2bf(x2[nt][1]);
                unsigned cc2 = (unsigned)(unsigned short)f2bf(x2[nt][2]);
                unsigned d = (unsigned)(unsigned short)f2bf(x2[nt][3]);
                w[nt * 2]     = a | (b << 16);
                w[nt * 2 + 1] = cc2 | (d << 16);
            }
            char* me = (char*)(msgp + (size_t)e * 512) + lane * 32;
            ((int4*)me)[0] = make_int4(w[0], w[1], w[2], w[3]);
            ((int4*)me)[1] = make_int4(w[4], w[5], w[6], w[7]);
        }

        sn = sn1; tn = tn1;
    }
#undef LDA
#undef LDH
#undef LFRAG
#undef MFMA
}

// ---------------- aggregation: wave per node, coalesced msg reads ----------------

__global__ __launch_bounds__(256)
void aggr_kernel(const short* __restrict__ msgp, const int* __restrict__ off,
                 const int* __restrict__ eidx, const float* __restrict__ rcnt,
                 float* __restrict__ h) {
    int n = blockIdx.x * 4 + (threadIdx.x >> 6);
    if (n >= NN) return;
    int lane = threadIdx.x & 63;
    int b = off[n], t = off[n + 1];
    float acc[8] = {0, 0, 0, 0, 0, 0, 0, 0};
    for (int s = b; s < t; s++) {
        int e = eidx[s];
        short8 mv = *(const short8*)&msgp[(size_t)e * 512 + lane * 8];
#pragma unroll
        for (int j = 0; j < 8; j++)
            acc[j] += __uint_as_float(((unsigned)(unsigned short)mv[j]) << 16);
    }
    float rc = rcnt[n];
    float* hn = h + (size_t)n * 512;
#pragma unroll
    for (int j = 0; j < 8; j++) {
        int m = lane * 8 + j;
        int ls = m >> 4, u = m & 15;
        int hidx = ((ls >> 4) * 4 + (u & 3)) * 64 + (u >> 2) * 16 + (ls & 15);
        hn[hidx] = acc[j] * rc;
    }
}

// ---------------- final projection + softmax ----------------

__global__ __launch_bounds__(256)
void out_kernel(const float* __restrict__ h, const float* __restrict__ ow,
                const float* __restrict__ ob, float* __restrict__ out)
{
    __shared__ __align__(16) float hl[16 * 516];
    __shared__ __align__(16) float wl[16 * 68];
    __shared__ float bl[16];
    const int tid = threadIdx.x;
    const int n0 = blockIdx.x * 16;
#pragma unroll
    for (int i = 0; i < 4; i++) {
        int idx = i * 256 + tid;
        wl[(idx >> 6) * 68 + (idx & 63)] = ow[idx];
    }
    if (tid < 16) bl[tid] = ob[tid];
#pragma unroll
    for (int i = 0; i < 32; i++) {
        int idx = i * 256 + tid; int nl = idx >> 9, j = idx & 511;
        hl[nl * 516 + j] = h[(size_t)(n0 + nl) * 512 + j];
    }
    __syncthreads();
    const int nl = tid >> 4, o = tid & 15;
    float acc = 0;
#pragma unroll 4
    for (int d4 = 0; d4 < 16; d4++) {
        float4 wv = *(const float4*)&wl[o * 68 + d4 * 4];
#pragma unroll
        for (int cc = 0; cc < 8; cc++) {
            float4 hv = *(const float4*)&hl[nl * 516 + cc * 64 + d4 * 4];
            acc += hv.x * wv.x + hv.y * wv.y + hv.z * wv.z + hv.w * wv.w;
        }
    }
    float z = acc + 8.0f * bl[o];
    float mxv = z;
#pragma unroll
    for (int m = 1; m < 16; m <<= 1) mxv = fmaxf(mxv, __shfl_xor(mxv, m));
    float ez = __expf(z - mxv);
    float sm = ez;
#pragma unroll
    for (int m = 1; m < 16; m <<= 1) sm += __shfl_xor(sm, m);
    out[(size_t)(n0 + nl) * 16 + o] = ez / sm;
}

// ---------------- launch ----------------

extern "C" void kernel_launch(void* const* d_in, const int* in_sizes, int n_in,
                              void* d_out, int out_size, void* d_ws, size_t ws_size,
                              hipStream_t stream)
{
    const float* x   = (const float*)d_in[0];
    const int*   ei  = (const int*)d_in[1];
    const float* nw  = (const float*)d_in[2];
    const float* nb  = (const float*)d_in[3];
    const float* bpw = (const float*)d_in[4];
    const float* bpb = (const float*)d_in[5];
    const float* ipw = (const float*)d_in[6];
    const float* ipb = (const float*)d_in[7];
    const float* opw = (const float*)d_in[8];
    const float* opb = (const float*)d_in[9];
    const float* g1  = (const float*)d_in[10];
    const float* b1  = (const float*)d_in[11];
    const float* g2  = (const float*)d_in[12];
    const float* b2  = (const float*)d_in[13];
    const float* f1w = (const float*)d_in[14];
    const float* f1b = (const float*)d_in[15];
    const float* f2w = (const float*)d_in[16];
    const float* f2b = (const float*)d_in[17];
    const float* ow  = (const float*)d_in[18];
    const float* ob  = (const float*)d_in[19];

    float* h0   = (float*)d_ws;                     // 25,600,000 f32
    short* msg  = (short*)(h0 + (size_t)NN * 512);  // 51,200,000 bf16
    int*   cnt  = (int*)(msg + (size_t)EE * 512);   // 50,000
    int*   off  = cnt + 50000;                      // 50,004 (padded)
    int*   fil  = off + 50004;                      // 50,000
    int*   eidx = fil + 50000;                      // 100,000
    float* rcnt = (float*)(eidx + 100000);          // 50,000
    short* wtb  = (short*)(rcnt + 50000);           // 2*28,672 (16B-aligned)

    // CSR build (edge_index constant; rebuilt every call for graph-capture safety)
    hipMemsetAsync(cnt, 0, 50000 * sizeof(int), stream);
    hipMemsetAsync(fil, 0, 50000 * sizeof(int), stream);
    count_kernel<<<(EE + 255) / 256, 256, 0, stream>>>(ei + EE, cnt);
    scan_kernel<<<1, 1024, 0, stream>>>(cnt, off);
    fill_kernel<<<(EE + 255) / 256, 256, 0, stream>>>(ei + EE, off, fil, eidx);
    recip_kernel<<<(NN + 255) / 256, 256, 0, stream>>>(cnt, rcnt);
    prep_frags<<<(LL * 28672 + 255) / 256, 256, 0, stream>>>(bpw, ipw, opw, f1w, f2w, wtb);
    embed_kernel<<<(NN * 512) / 256, 256, 0, stream>>>(x, nw, nb, h0);

    layer_kernel<<<GRID, 1024, 0, stream>>>(h0, msg, ei, ei + EE, wtb,
                                            bpb, ipb, opb, g1, b1, g2, b2, f1b, f2b);
    aggr_kernel<<<(NN + 3) / 4, 256, 0, stream>>>(msg, off, eidx, rcnt, h0);
    layer_kernel<<<GRID, 1024, 0, stream>>>(h0, msg, ei, ei + EE, wtb + 28672,
                                            bpb + 64, ipb + 192, opb + 64,
                                            g1 + 64, b1 + 64, g2 + 64, b2 + 64, f1b + 64, f2b + 64);
    aggr_kernel<<<(NN + 3) / 4, 256, 0, stream>>>(msg, off, eidx, rcnt, h0);
    out_kernel<<<NN / 16, 256, 0, stream>>>(h0, ow, ob, (float*)d_out);
}

// Round 9
// 787.826 us; speedup vs baseline: 3.9051x; 1.4296x over previous
//
#include <hip/hip_runtime.h>
#include <hip/hip_bf16.h>

#define NN 50000
#define EE 100000
#define LL 2

typedef __attribute__((ext_vector_type(8))) short short8;
typedef __attribute__((ext_vector_type(4))) float f32x4;

__device__ __forceinline__ short f2bf(float x) {
    __hip_bfloat16 b = __float2bfloat16(x);   // HW RNE
    short s;
    __builtin_memcpy(&s, &b, 2);
    return s;
}
__device__ __forceinline__ unsigned us(short v) { return (unsigned)(unsigned short)v; }

// ---------------- CSR / prep kernels ----------------

__global__ __launch_bounds__(256)
void count_kernel(const int* __restrict__ tgt, int* __restrict__ cnt) {
    int e = blockIdx.x * 256 + threadIdx.x;
    if (e < EE) atomicAdd(&cnt[tgt[e]], 1);
}

__global__ __launch_bounds__(1024)
void scan_kernel(const int* __restrict__ cnt, int* __restrict__ off) {
    __shared__ int tmp[1024];
    __shared__ int carry;
    if (threadIdx.x == 0) carry = 0;
    __syncthreads();
    for (int base = 0; base < NN; base += 1024) {
        int i = base + threadIdx.x;
        int v = (i < NN) ? cnt[i] : 0;
        tmp[threadIdx.x] = v;
        __syncthreads();
        for (int d = 1; d < 1024; d <<= 1) {
            int t = (threadIdx.x >= d) ? tmp[threadIdx.x - d] : 0;
            __syncthreads();
            tmp[threadIdx.x] += t;
            __syncthreads();
        }
        int incl = tmp[threadIdx.x] + carry;
        if (i < NN) off[i + 1] = incl;
        __syncthreads();
        if (threadIdx.x == 1023) carry = incl;
        __syncthreads();
    }
    if (threadIdx.x == 0) off[0] = 0;
}

__global__ __launch_bounds__(256)
void fill_kernel(const int* __restrict__ tgt, const int* __restrict__ off,
                 int* __restrict__ fil, int* __restrict__ eidx) {
    int e = blockIdx.x * 256 + threadIdx.x;
    if (e < EE) {
        int t = tgt[e];
        int s = atomicAdd(&fil[t], 1);
        eidx[off[t] + s] = e;
    }
}

__global__ __launch_bounds__(256)
void recip_kernel(const int* __restrict__ cnt, float* __restrict__ rcnt) {
    int n = blockIdx.x * 256 + threadIdx.x;
    if (n < NN) rcnt[n] = 1.0f / fmaxf((float)cnt[n], 1.0f);
}

__global__ __launch_bounds__(256)
void embed_kernel(const float* __restrict__ x, const float* __restrict__ nw,
                  const float* __restrict__ nb, float* __restrict__ h0) {
    int gid = blockIdx.x * 256 + threadIdx.x;
    if (gid >= NN * 512) return;
    int n = gid >> 9, j = gid & 511;
    h0[gid] = x[n * 8 + (j >> 6)] * nw[j] + nb[j];
}

// Build bf16 B-fragments for all weights.
// Frag f (1024 B): lane l, elem j holds W[nt*16 + (l&15)][ks*32 + (l>>4)*8 + j]
// Order: f 0..7 bproj | 8..31 ipw | 32..39 opw | 40..47 ff1 | 48..55 ff2.
__global__ __launch_bounds__(256)
void prep_frags(const float* __restrict__ bpw, const float* __restrict__ ipw,
                const float* __restrict__ opw, const float* __restrict__ f1w,
                const float* __restrict__ f2w, short* __restrict__ wtb) {
    int gid = blockIdx.x * 256 + threadIdx.x;
    if (gid >= LL * 28672) return;
    int l = gid / 28672, u = gid % 28672;
    int f = u >> 9;
    int el = u & 511;
    int ln = el >> 3, j = el & 7;
    int row16 = ln & 15, kg = ln >> 4;
    const float* W;
    int t;
    if (f < 8)       { W = bpw + l * 4096;  t = f; }
    else if (f < 32) { W = ipw + l * 12288; t = f - 8; }
    else if (f < 40) { W = opw + l * 4096;  t = f - 32; }
    else if (f < 48) { W = f1w + l * 4096;  t = f - 40; }
    else             { W = f2w + l * 4096;  t = f - 48; }
    int nt = t >> 1, ks = t & 1;
    int r = nt * 16 + row16, col = ks * 32 + kg * 8 + j;
    wtb[(size_t)l * 28672 + u] = f2bf(W[r * 64 + col]);
}

// Fused j-role weights: M_kb = W_k @ W_b, M_vb = W_v @ W_b (bf16 frags, same layout).
// fwb layout: [l][mat(0=K,1=V)][8 frags][512]
__global__ __launch_bounds__(256)
void prep_fused(const float* __restrict__ bpw, const float* __restrict__ ipw,
                short* __restrict__ fwb) {
    int gid = blockIdx.x * 256 + threadIdx.x;
    if (gid >= LL * 8192) return;
    int l = gid / 8192, u2 = gid % 8192;
    int mat = u2 / 4096, u = u2 % 4096;
    int f = u >> 9, el = u & 511;
    int ln = el >> 3, j = el & 7;
    int row16 = ln & 15, kg = ln >> 4;
    int nt = f >> 1, ks = f & 1;
    int o = nt * 16 + row16, kcol = ks * 32 + kg * 8 + j;
    const float* Wx = ipw + l * 12288 + (64 + mat * 64 + o) * 64;
    const float* Wb = bpw + l * 4096;
    float s = 0.f;
#pragma unroll 8
    for (int m = 0; m < 64; m++) s = fmaf(Wx[m], Wb[m * 64 + kcol], s);
    fwb[gid] = f2bf(s);
}

// Fused biases: c_kb/c_vb = b_{k,v} + W_{k,v} @ b_b. fbias layout [l][128] (kb|vb).
__global__ __launch_bounds__(256)
void prep_fbias(const float* __restrict__ bpb, const float* __restrict__ ipw,
                const float* __restrict__ ipb, float* __restrict__ fbias) {
    int tid = blockIdx.x * 256 + threadIdx.x;
    if (tid >= LL * 128) return;
    int l = tid / 128, mo = tid % 128;
    int mat = mo / 64, o = mo % 64;
    const float* Wx = ipw + l * 12288 + (64 + mat * 64 + o) * 64;
    float s = ipb[l * 192 + 64 + mat * 64 + o];
#pragma unroll 8
    for (int m = 0; m < 64; m++) s = fmaf(Wx[m], bpb[l * 64 + m], s);
    fbias[tid] = s;
}

// ---------------- device helpers ----------------

__device__ __forceinline__ void ln64(float x[4][4], const float* gv, const float* bv, int c) {
    float gg[4], bb[4];
#pragma unroll
    for (int nt = 0; nt < 4; nt++) { gg[nt] = gv[nt * 16 + c]; bb[nt] = bv[nt * 16 + c]; }
#pragma unroll
    for (int r = 0; r < 4; r++) {
        float s1 = x[0][r] + x[1][r] + x[2][r] + x[3][r];
        float s2 = x[0][r] * x[0][r];
#pragma unroll
        for (int nt = 1; nt < 4; nt++) s2 = fmaf(x[nt][r], x[nt][r], s2);
#pragma unroll
        for (int m = 1; m < 16; m <<= 1) { s1 += __shfl_xor(s1, m); s2 += __shfl_xor(s2, m); }
        float mean = s1 * 0.015625f;
        float var = fmaf(s2, 0.015625f, -mean * mean);
        float rs = rsqrtf(var + 1e-5f);
#pragma unroll
        for (int nt = 0; nt < 4; nt++) x[nt][r] = fmaf((x[nt][r] - mean) * rs, gg[nt], bb[nt]);
    }
}

__device__ __forceinline__ short8 cvt8(float4 lo, float4 hi) {
    short8 r;
    r[0] = f2bf(lo.x); r[1] = f2bf(lo.y); r[2] = f2bf(lo.z); r[3] = f2bf(lo.w);
    r[4] = f2bf(hi.x); r[5] = f2bf(hi.y); r[6] = f2bf(hi.z); r[7] = f2bf(hi.w);
    return r;
}

#define MFMA(a, b, cc) __builtin_amdgcn_mfma_f32_16x16x32_bf16((a), (b), (cc), 0, 0, 0)

// ---------------- fused 2-edges-per-wave layer kernel ----------------
// Shared LDS:
//  [0,24576)      in_proj frags (Wq LF0-7, Wk LF8-15, Wv LF16-23)
//  [24576,40960)  fused frags  (M_kb LF24-31, M_vb LF32-39)
//  [40960,49152)  opw frags    (LF40-47)
//  [49152,57344)  ff1 frags    (LF48-55)
//  [57344,60416)  biases 768 f32
//  [60416,158720) 8 waves x 12288: tKA 0 | tKB 2048 | tQA 4096 (=bufB) | tQB 6144 | VtA 8192 | VtB 10240

__global__ __launch_bounds__(512, 2)
void layer_kernel(const float* __restrict__ h_in, short* __restrict__ msgp,
                  const int* __restrict__ src, const int* __restrict__ tgt,
                  const short* __restrict__ wfr, const short* __restrict__ fwb,
                  const float* __restrict__ fbl,
                  const float* __restrict__ ipb, const float* __restrict__ opb,
                  const float* __restrict__ g1v, const float* __restrict__ b1v,
                  const float* __restrict__ g2v, const float* __restrict__ b2v,
                  const float* __restrict__ f1b, const float* __restrict__ f2b)
{
    __shared__ __align__(16) char smem[158720];
    const int tid = threadIdx.x, wv = tid >> 6, lane = tid & 63;
    const int g = lane >> 4, c = lane & 15;
    const int swz = (c & 7) << 4;

    {   // stage weights + biases
        int4* dw = (int4*)smem;
        const int4* s1 = (const int4*)(wfr + 8 * 512);    // frags 8..31 -> [0,24576)
        for (int i = tid; i < 1536; i += 512) dw[i] = s1[i];
        const int4* s2 = (const int4*)fwb;                // fused 16 frags -> [24576,40960)
        for (int i = tid; i < 1024; i += 512) dw[1536 + i] = s2[i];
        const int4* s3 = (const int4*)(wfr + 32 * 512);   // frags 32..47 -> [40960,57344)
        for (int i = tid; i < 1024; i += 512) dw[2560 + i] = s3[i];
        float* bl = (float*)(smem + 57344);
        for (int i = tid; i < 768; i += 512) {            // FIX: loop, not single pass
            float v;
            if (i < 192)      v = ipb[i];
            else if (i < 320) v = fbl[i - 192];
            else if (i < 384) v = opb[i - 320];
            else if (i < 448) v = g1v[i - 384];
            else if (i < 512) v = b1v[i - 448];
            else if (i < 576) v = g2v[i - 512];
            else if (i < 640) v = b2v[i - 576];
            else if (i < 704) v = f1b[i - 640];
            else              v = f2b[i - 704];
            bl[i] = v;
        }
    }
    __syncthreads();

    // ff2 frags global -> regs, loop-invariant
    const short8* gw = (const short8*)wfr;
    short8 wf2[8];
#pragma unroll
    for (int i = 0; i < 8; i++) wf2[i] = gw[(48 + i) * 64 + lane];

    char* wb  = smem + 60416 + wv * 12288;
    char* tKA = wb;          char* tKB = wb + 2048;
    char* tQA = wb + 4096;   char* tQB = wb + 6144;
    char* VtA = wb + 8192;   char* VtB = wb + 10240;
    char* bufB = tQA;        // overlay after attention reads
    const float* bl = (const float*)(smem + 57344);
    const f32x4 zf = {};
    const short8 z8 = {};

    // defensive: zero garbage-query rows 8-15 of both Q tiles once
    *(int4*)(tQA + 1024 + lane * 16) = make_int4(0, 0, 0, 0);
    *(int4*)(tQB + 1024 + lane * 16) = make_int4(0, 0, 0, 0);

#define LF(i)      (*(const short8*)&smem[(i) * 1024 + lane * 16])
#define LDA(B, ks) (*(const short8*)&(B)[c * 128 + (((ks) * 64 + g * 16) ^ swz)])
#define LDH(B, hh) (*(const short8*)&(B)[c * 128 + (((hh) * 32 + (g & 1) * 16) ^ swz)])

    const int P0 = blockIdx.x * 8 + wv;     // 256 blocks * 8 waves = 2048
    for (int p = P0; p < EE / 2; p += 2048) {
        const int eA = 2 * p, eB = 2 * p + 1;
        const int tnA = tgt[eA], snA = src[eA];
        const int tnB = tgt[eB], snB = src[eB];
        const float* hA  = h_in + (size_t)tnA * 512;
        const float* hB  = h_in + (size_t)tnB * 512;
        const float* hsA = h_in + (size_t)snA * 512;
        const float* hsB = h_in + (size_t)snB * 512;

        // residual x_i (fp32): packed row m=g*4+r -> edge (g<2?A:B), token (g&1)*4+r
        const float* hres = (g < 2) ? hA : hB;
        float xc[4][4];
#pragma unroll
        for (int nt = 0; nt < 4; nt++)
#pragma unroll
            for (int r = 0; r < 4; r++)
                xc[nt][r] = hres[((g & 1) * 4 + r) * 64 + nt * 16 + c];

        // A-frags: X1 row c = (c<8 ? hA tok c : hB tok c-8); X2 from hsA/hsB
        const float* rowA = (c < 8) ? (hA + c * 64) : (hB + (c - 8) * 64);
        const float* rowB = (c < 8) ? (hsA + c * 64) : (hsB + (c - 8) * 64);
        short8 a0 = cvt8(*(const float4*)(rowA + g * 8), *(const float4*)(rowA + g * 8 + 4));
        short8 a1 = cvt8(*(const float4*)(rowA + 32 + g * 8), *(const float4*)(rowA + 32 + g * 8 + 4));
        short8 b0 = cvt8(*(const float4*)(rowB + g * 8), *(const float4*)(rowB + g * 8 + 4));
        short8 b1f = cvt8(*(const float4*)(rowB + 32 + g * 8), *(const float4*)(rowB + 32 + g * 8 + 4));

        char* tK = (g < 2) ? tKA : tKB;
        char* tQ = (g < 2) ? tQA : tQB;
        char* Vt = (g < 2) ? VtA : VtB;
        const int lr4 = (g & 1) * 4;

        // ---- i-role Q,K,V (24 MFMA), store into per-edge tiles ----
#pragma unroll
        for (int nt = 0; nt < 4; nt++) {
            f32x4 qv = MFMA(a1, LF(nt * 2 + 1),      MFMA(a0, LF(nt * 2),      zf));
            f32x4 kv = MFMA(a1, LF(8 + nt * 2 + 1),  MFMA(a0, LF(8 + nt * 2),  zf));
            f32x4 vv = MFMA(a1, LF(16 + nt * 2 + 1), MFMA(a0, LF(16 + nt * 2), zf));
            float bq = bl[nt * 16 + c], bk = bl[64 + nt * 16 + c], bv = bl[128 + nt * 16 + c];
            int col2 = (nt * 16 + c) * 2;
#pragma unroll
            for (int r = 0; r < 4; r++) {
                int l2 = lr4 + r;    // 0..7
                int so = col2 ^ (l2 << 4);
                *(short*)(tK + l2 * 128 + so) = f2bf(kv[r] + bk);
                *(short*)(tQ + l2 * 128 + so) = f2bf(qv[r] + bq);
            }
            unsigned lo = us(f2bf(vv[0] + bv)) | (us(f2bf(vv[1] + bv)) << 16);
            unsigned hi = us(f2bf(vv[2] + bv)) | (us(f2bf(vv[3] + bv)) << 16);
            *(uint2*)(Vt + (nt * 16 + c) * 32 + (g & 1) * 8) = make_uint2(lo, hi);
        }

        // ---- j-role K,V via fused weights (16 MFMA) ----
#pragma unroll
        for (int nt = 0; nt < 4; nt++) {
            f32x4 kj = MFMA(b1f, LF(24 + nt * 2 + 1), MFMA(b0, LF(24 + nt * 2), zf));
            f32x4 vj = MFMA(b1f, LF(32 + nt * 2 + 1), MFMA(b0, LF(32 + nt * 2), zf));
            float bk = bl[192 + nt * 16 + c], bv = bl[256 + nt * 16 + c];
            int col2 = (nt * 16 + c) * 2;
#pragma unroll
            for (int r = 0; r < 4; r++) {
                int l2 = lr4 + r;
                *(short*)(tK + (8 + l2) * 128 + (col2 ^ (l2 << 4))) = f2bf(kj[r] + bk);
            }
            unsigned lo = us(f2bf(vj[0] + bv)) | (us(f2bf(vj[1] + bv)) << 16);
            unsigned hi = us(f2bf(vj[2] + bv)) | (us(f2bf(vj[3] + bv)) << 16);
            *(uint2*)(Vt + (nt * 16 + c) * 32 + 16 + (g & 1) * 8) = make_uint2(lo, hi);
        }

        // ---- attention, both edges (queries 0-7 real; cols 8-15 zero/garbage, discarded) ----
        float ovA[4][4], ovB[4][4];
#pragma unroll
        for (int hh = 0; hh < 4; hh++) {
            short8 kfA = LDH(tKA, hh), qfA = LDH(tQA, hh);
            short8 kfB = LDH(tKB, hh), qfB = LDH(tQB, hh);
            if (lane >= 32) { kfA = z8; kfB = z8; }
            f32x4 stA = MFMA(kfA, qfA, zf);
            f32x4 stB = MFMA(kfB, qfB, zf);
            float pA[4], pB[4];
#pragma unroll
            for (int r = 0; r < 4; r++) { pA[r] = stA[r] * 0.25f; pB[r] = stB[r] * 0.25f; }
            float mA = fmaxf(fmaxf(pA[0], pA[1]), fmaxf(pA[2], pA[3]));
            float mB = fmaxf(fmaxf(pB[0], pB[1]), fmaxf(pB[2], pB[3]));
            mA = fmaxf(mA, __shfl_xor(mA, 16)); mB = fmaxf(mB, __shfl_xor(mB, 16));
            mA = fmaxf(mA, __shfl_xor(mA, 32)); mB = fmaxf(mB, __shfl_xor(mB, 32));
            float sA = 0.f, sB = 0.f;
#pragma unroll
            for (int r = 0; r < 4; r++) {
                pA[r] = __expf(pA[r] - mA); sA += pA[r];
                pB[r] = __expf(pB[r] - mB); sB += pB[r];
            }
            sA += __shfl_xor(sA, 16); sB += __shfl_xor(sB, 16);
            sA += __shfl_xor(sA, 32); sB += __shfl_xor(sB, 32);
            float iA = 1.0f / sA, iB = 1.0f / sB;
#pragma unroll
            for (int r = 0; r < 4; r++) { pA[r] *= iA; pB[r] *= iB; }

            short8 paA, paB;
#pragma unroll
            for (int j = 0; j < 8; j++) {
                int srcl = g * 32 + ((j >> 2) << 4) + c;
                paA[j] = f2bf(__shfl(pA[j & 3], srcl));
                paB[j] = f2bf(__shfl(pB[j & 3], srcl));
            }
            if (lane >= 32) { paA = z8; paB = z8; }
            short8 vbA = *(const short8*)&VtA[(hh * 16 + c) * 32 + (g & 1) * 16];
            short8 vbB = *(const short8*)&VtB[(hh * 16 + c) * 32 + (g & 1) * 16];
            f32x4 oA = MFMA(paA, vbA, zf);
            f32x4 oB = MFMA(paB, vbB, zf);
#pragma unroll
            for (int r = 0; r < 4; r++) { ovA[hh][r] = oA[r]; ovB[hh][r] = oB[r]; }
        }

        // ---- pack O rows 0-7 of both edges into one 16-row tile (bufB = tQA, now dead) ----
        if (lane < 32) {
#pragma unroll
            for (int hh = 0; hh < 4; hh++)
#pragma unroll
                for (int r = 0; r < 4; r++) {
                    int m = g * 4 + r;  // 0..7
                    int so = ((hh * 16 + c) * 2) ^ (m << 4);
                    *(short*)&bufB[m * 128 + so] = f2bf(ovA[hh][r]);
                    *(short*)&bufB[(8 + m) * 128 + so] = f2bf(ovB[hh][r]);
                }
        }

        // ---- out_proj + residual + LN1 ----
        short8 c0 = LDA(bufB, 0), c1 = LDA(bufB, 1);
        float x1[4][4];
#pragma unroll
        for (int nt = 0; nt < 4; nt++) {
            f32x4 acc = MFMA(c1, LF(40 + nt * 2 + 1), MFMA(c0, LF(40 + nt * 2), zf));
            float bo = bl[320 + nt * 16 + c];
#pragma unroll
            for (int r = 0; r < 4; r++) x1[nt][r] = acc[r] + bo + xc[nt][r];
        }
        ln64(x1, bl + 384, bl + 448, c);

        // ---- FF ----
#pragma unroll
        for (int nt = 0; nt < 4; nt++)
#pragma unroll
            for (int r = 0; r < 4; r++) {
                int m = g * 4 + r;
                *(short*)&bufB[m * 128 + (((nt * 16 + c) * 2) ^ ((m & 7) << 4))] = f2bf(x1[nt][r]);
            }
        c0 = LDA(bufB, 0); c1 = LDA(bufB, 1);
#pragma unroll
        for (int nt = 0; nt < 4; nt++) {
            f32x4 acc = MFMA(c1, LF(48 + nt * 2 + 1), MFMA(c0, LF(48 + nt * 2), zf));
            float bf = bl[640 + nt * 16 + c];
#pragma unroll
            for (int r = 0; r < 4; r++) {
                float y = fmaxf(acc[r] + bf, 0.0f);
                int m = g * 4 + r;
                *(short*)&bufB[m * 128 + (((nt * 16 + c) * 2) ^ ((m & 7) << 4))] = f2bf(y);
            }
        }
        c0 = LDA(bufB, 0); c1 = LDA(bufB, 1);
        float x2[4][4];
#pragma unroll
        for (int nt = 0; nt < 4; nt++) {
            f32x4 acc = MFMA(c1, wf2[nt * 2 + 1], MFMA(c0, wf2[nt * 2], zf));
            float bf = bl[704 + nt * 16 + c];
#pragma unroll
            for (int r = 0; r < 4; r++) x2[nt][r] = acc[r] + bf + x1[nt][r];
        }
        ln64(x2, bl + 512, bl + 576, c);

        // ---- pack msg: lanes<32 -> edge A, lanes>=32 -> edge B ----
        {
            unsigned w[8];
#pragma unroll
            for (int nt = 0; nt < 4; nt++) {
                unsigned a = us(f2bf(x2[nt][0]));
                unsigned b = us(f2bf(x2[nt][1]));
                unsigned cc2 = us(f2bf(x2[nt][2]));
                unsigned d = us(f2bf(x2[nt][3]));
                w[nt * 2]     = a | (b << 16);
                w[nt * 2 + 1] = cc2 | (d << 16);
            }
            int eOut = (lane < 32) ? eA : eB;
            int ll = lane & 31;
            char* me = (char*)(msgp + (size_t)eOut * 512) + ll * 32;
            ((int4*)me)[0] = make_int4(w[0], w[1], w[2], w[3]);
            ((int4*)me)[1] = make_int4(w[4], w[5], w[6], w[7]);
        }
    }
#undef LF
#undef LDA
#undef LDH
}

// ---------------- aggregation: wave per node, coalesced msg reads ----------------

__global__ __launch_bounds__(256)
void aggr_kernel(const short* __restrict__ msgp, const int* __restrict__ off,
                 const int* __restrict__ eidx, const float* __restrict__ rcnt,
                 float* __restrict__ h) {
    int n = blockIdx.x * 4 + (threadIdx.x >> 6);
    if (n >= NN) return;
    int lane = threadIdx.x & 63;
    int b = off[n], t = off[n + 1];
    float acc[8] = {0, 0, 0, 0, 0, 0, 0, 0};
    for (int s = b; s < t; s++) {
        int e = eidx[s];
        short8 mv = *(const short8*)&msgp[(size_t)e * 512 + lane * 8];
#pragma unroll
        for (int j = 0; j < 8; j++)
            acc[j] += __uint_as_float(((unsigned)(unsigned short)mv[j]) << 16);
    }
    float rc = rcnt[n];
    float* hn = h + (size_t)n * 512;
#pragma unroll
    for (int j = 0; j < 8; j++) {
        int m = lane * 8 + j;
        int ls = m >> 4, u = m & 15;
        int hidx = ((ls >> 4) * 4 + (u & 3)) * 64 + (u >> 2) * 16 + (ls & 15);
        hn[hidx] = acc[j] * rc;
    }
}

// ---------------- final projection + softmax ----------------

__global__ __launch_bounds__(256)
void out_kernel(const float* __restrict__ h, const float* __restrict__ ow,
                const float* __restrict__ ob, float* __restrict__ out)
{
    __shared__ __align__(16) float hl[16 * 516];
    __shared__ __align__(16) float wl[16 * 68];
    __shared__ float blr[16];
    const int tid = threadIdx.x;
    const int n0 = blockIdx.x * 16;
#pragma unroll
    for (int i = 0; i < 4; i++) {
        int idx = i * 256 + tid;
        wl[(idx >> 6) * 68 + (idx & 63)] = ow[idx];
    }
    if (tid < 16) blr[tid] = ob[tid];
#pragma unroll
    for (int i = 0; i < 32; i++) {
        int idx = i * 256 + tid; int nl = idx >> 9, j = idx & 511;
        hl[nl * 516 + j] = h[(size_t)(n0 + nl) * 512 + j];
    }
    __syncthreads();
    const int nl = tid >> 4, o = tid & 15;
    float acc = 0;
#pragma unroll 4
    for (int d4 = 0; d4 < 16; d4++) {
        float4 wv = *(const float4*)&wl[o * 68 + d4 * 4];
#pragma unroll
        for (int cc = 0; cc < 8; cc++) {
            float4 hv = *(const float4*)&hl[nl * 516 + cc * 64 + d4 * 4];
            acc += hv.x * wv.x + hv.y * wv.y + hv.z * wv.z + hv.w * wv.w;
        }
    }
    float z = acc + 8.0f * blr[o];
    float mxv = z;
#pragma unroll
    for (int m = 1; m < 16; m <<= 1) mxv = fmaxf(mxv, __shfl_xor(mxv, m));
    float ez = __expf(z - mxv);
    float sm = ez;
#pragma unroll
    for (int m = 1; m < 16; m <<= 1) sm += __shfl_xor(sm, m);
    out[(size_t)(n0 + nl) * 16 + o] = ez / sm;
}

// ---------------- launch ----------------

extern "C" void kernel_launch(void* const* d_in, const int* in_sizes, int n_in,
                              void* d_out, int out_size, void* d_ws, size_t ws_size,
                              hipStream_t stream)
{
    const float* x   = (const float*)d_in[0];
    const int*   ei  = (const int*)d_in[1];
    const float* nw  = (const float*)d_in[2];
    const float* nb  = (const float*)d_in[3];
    const float* bpw = (const float*)d_in[4];
    const float* bpb = (const float*)d_in[5];
    const float* ipw = (const float*)d_in[6];
    const float* ipb = (const float*)d_in[7];
    const float* opw = (const float*)d_in[8];
    const float* opb = (const float*)d_in[9];
    const float* g1  = (const float*)d_in[10];
    const float* b1  = (const float*)d_in[11];
    const float* g2  = (const float*)d_in[12];
    const float* b2  = (const float*)d_in[13];
    const float* f1w = (const float*)d_in[14];
    const float* f1b = (const float*)d_in[15];
    const float* f2w = (const float*)d_in[16];
    const float* f2b = (const float*)d_in[17];
    const float* ow  = (const float*)d_in[18];
    const float* ob  = (const float*)d_in[19];

    float* h0    = (float*)d_ws;                     // 25,600,000 f32 (102.4 MB)
    short* msg   = (short*)(h0 + (size_t)NN * 512);  // 51,200,000 bf16 (102.4 MB)
    int*   cnt   = (int*)(msg + (size_t)EE * 512);   // 50,000
    int*   off   = cnt + 50000;                      // 50,004
    int*   fil   = off + 50004;                      // 50,000
    int*   eidx  = fil + 50000;                      // 100,000
    float* rcnt  = (float*)(eidx + 100000);          // 50,000
    short* wtb   = (short*)(rcnt + 50000);           // 2*28,672 bf16
    short* fwb   = wtb + LL * 28672;                 // 2*8,192 bf16
    float* fbias = (float*)(fwb + LL * 8192);        // 2*128 f32

    // CSR build (edge_index constant; rebuilt every call for graph-capture safety)
    hipMemsetAsync(cnt, 0, 50000 * sizeof(int), stream);
    hipMemsetAsync(fil, 0, 50000 * sizeof(int), stream);
    count_kernel<<<(EE + 255) / 256, 256, 0, stream>>>(ei + EE, cnt);
    scan_kernel<<<1, 1024, 0, stream>>>(cnt, off);
    fill_kernel<<<(EE + 255) / 256, 256, 0, stream>>>(ei + EE, off, fil, eidx);
    recip_kernel<<<(NN + 255) / 256, 256, 0, stream>>>(cnt, rcnt);
    prep_frags<<<(LL * 28672 + 255) / 256, 256, 0, stream>>>(bpw, ipw, opw, f1w, f2w, wtb);
    prep_fused<<<(LL * 8192 + 255) / 256, 256, 0, stream>>>(bpw, ipw, fwb);
    prep_fbias<<<1, 256, 0, stream>>>(bpb, ipw, ipb, fbias);
    embed_kernel<<<(NN * 512) / 256, 256, 0, stream>>>(x, nw, nb, h0);

    for (int l = 0; l < LL; l++) {
        layer_kernel<<<256, 512, 0, stream>>>(
            h0, msg, ei, ei + EE, wtb + l * 28672, fwb + l * 8192, fbias + l * 128,
            ipb + l * 192, opb + l * 64, g1 + l * 64, b1 + l * 64,
            g2 + l * 64, b2 + l * 64, f1b + l * 64, f2b + l * 64);
        aggr_kernel<<<(NN + 3) / 4, 256, 0, stream>>>(msg, off, eidx, rcnt, h0);
    }
    out_kernel<<<NN / 16, 256, 0, stream>>>(h0, ow, ob, (float*)d_out);
}